// Round 1
// baseline (139.547 us; speedup 1.0000x reference)
//
#include <hip/hip_runtime.h>
#include <cstdint>

#define E_DIM   1024
#define DH      32
#define M_FEAT  256
#define BT      16384

typedef __attribute__((ext_vector_type(8))) short bf16x8;
typedef __attribute__((ext_vector_type(4))) float f32x4;

// ws layout (shorts): proj W in MFMA-fragment order, flat = (nt*32 + sub)*512 + lane*8
#define WP_H_OFF 0
#define WP_L_OFF 65536

// ---- cheap 2-term bf16 split: h = trunc16(f), l = trunc16(f - h) ----
__device__ __forceinline__ unsigned perm_hi2(unsigned lo_src, unsigned hi_src) {
#if __has_builtin(__builtin_amdgcn_perm)
    return __builtin_amdgcn_perm(hi_src, lo_src, 0x07060302u);
#else
    return (lo_src >> 16) | (hi_src & 0xFFFF0000u);
#endif
}

__device__ __forceinline__ void split2(float f0, float f1, unsigned& ph, unsigned& pl) {
    unsigned u0 = __builtin_bit_cast(unsigned, f0);
    unsigned u1 = __builtin_bit_cast(unsigned, f1);
    ph = perm_hi2(u0, u1);
    float d0 = f0 - __builtin_bit_cast(float, u0 & 0xFFFF0000u);
    float d1 = f1 - __builtin_bit_cast(float, u1 & 0xFFFF0000u);
    pl = perm_hi2(__builtin_bit_cast(unsigned, d0), __builtin_bit_cast(unsigned, d1));
}

__device__ __forceinline__ void split8(const float4& a, const float4& b,
                                       uint4& uh, uint4& ul) {
    split2(a.x, a.y, uh.x, ul.x);
    split2(a.z, a.w, uh.y, ul.y);
    split2(b.x, b.y, uh.z, ul.z);
    split2(b.z, b.w, uh.w, ul.w);
}

// ---------- prep: 32 blocks, each a 64-k half-slab; LDS transpose -> fragment order ----------
__global__ __launch_bounds__(256) void k_prep(
    const float* __restrict__ Wq, const float* __restrict__ Wk,
    short* __restrict__ ws)
{
    __shared__ float wlds[64 * 36];    // [k 0..63][n 0..31], stride 36 floats
    const int b = blockIdx.x, tid = threadIdx.x;
    const float* __restrict__ src = (b < 16) ? Wq : Wk;
    const int k0 = (b & 15) * 64;
    const int nbase = (b < 16) ? 0 : 32;
#pragma unroll
    for (int it = 0; it < 2; ++it) {               // coalesced read 64x32 floats
        int f = it * 256 + tid;                    // float4 index
        int k = f >> 3, c4 = f & 7;
        float4 v = *(const float4*)(src + (size_t)(k0 + k) * DH + c4 * 4);
        *(float4*)&wlds[k * 36 + c4 * 4] = v;
    }
    __syncthreads();
    const int n = tid >> 3, kq = tid & 7;
    const int n_g = nbase + n;
    const int nt = n_g >> 4, ln = n_g & 15;
#pragma unroll
    for (int rep = 0; rep < 2; ++rep) {
        int kk = rep * 8 + kq;                     // k-quad within this 64-slab
        int k_g = k0 + kk * 4;
        float f0 = wlds[(kk * 4 + 0) * 36 + n];
        float f1 = wlds[(kk * 4 + 1) * 36 + n];
        float f2 = wlds[(kk * 4 + 2) * 36 + n];
        float f3 = wlds[(kk * 4 + 3) * 36 + n];
        uint2 ph, pl;
        split2(f0, f1, ph.x, pl.x);
        split2(f2, f3, ph.y, pl.y);
        int sub = k_g >> 5;                        // global 32-k subchunk 0..31
        int gq = (k_g >> 3) & 3, j0 = k_g & 7;
        int lane = gq * 16 + ln;
        size_t flat = ((size_t)(nt * 32 + sub)) * 512 + lane * 8 + j0;
        *(uint2*)(ws + WP_H_OFF + flat) = ph;
        *(uint2*)(ws + WP_L_OFF + flat) = pl;
    }
}

// ---------- fused main: barrier-free phase 1, A-fragments direct from global ----------
// wave wv: token-half th=wv>>1 (rows th*16..+15), col-half nh=wv&1 (n-tiles 2nh,2nh+1)
#define TB 32
#define QS 68    // qk row stride in floats
#define ZS 40    // z row stride in shorts

__global__ __launch_bounds__(256, 2) void k_main(
    const float* __restrict__ x, const float* __restrict__ bq,
    const float* __restrict__ bk, const short* __restrict__ ws,
    const float* __restrict__ w, float* __restrict__ out)
{
    __shared__ __align__(16) float qk_f[TB * QS];
    __shared__ __align__(16) short zh_s[TB * ZS];
    __shared__ __align__(16) short zl_s[TB * ZS];
    __shared__ float lnA_f[TB];

    const int tid  = threadIdx.x;
    const int lane = tid & 63;
    const int wv   = __builtin_amdgcn_readfirstlane(tid >> 6);  // 0..3
    const int ln15 = lane & 15;
    const int g    = lane >> 4;                                  // 0..3
    const long t0  = (long)blockIdx.x * TB;

    const int th = wv >> 1;            // token half 0..1
    const int nh = wv & 1;             // column half 0..1

    // -------- Phase 1: C[32 tok][64] = x @ [Wq|Wk], no LDS, no barriers --------
    // A fragment direct from global: lane holds row ln15, k = g*8..g*8+7
    const float* __restrict__ xA = x + (t0 + th * 16 + ln15) * (size_t)E_DIM + g * 8;
    const short* __restrict__ wB0h = ws + WP_H_OFF + (size_t)((nh * 2 + 0) * 32) * 512 + lane * 8;
    const short* __restrict__ wB0l = ws + WP_L_OFF + (size_t)((nh * 2 + 0) * 32) * 512 + lane * 8;
    const short* __restrict__ wB1h = ws + WP_H_OFF + (size_t)((nh * 2 + 1) * 32) * 512 + lane * 8;
    const short* __restrict__ wB1l = ws + WP_L_OFF + (size_t)((nh * 2 + 1) * 32) * 512 + lane * 8;

    f32x4 acc0 = {0.f, 0.f, 0.f, 0.f};   // n-tile nh*2+0
    f32x4 acc1 = {0.f, 0.f, 0.f, 0.f};   // n-tile nh*2+1

    float4 aCur[4][2], aNxt[4][2];
#pragma unroll
    for (int j = 0; j < 4; ++j) {
        aCur[j][0] = *(const float4*)(xA + j * 32);
        aCur[j][1] = *(const float4*)(xA + j * 32 + 4);
    }
#pragma unroll
    for (int p = 0; p < 8; ++p) {
        if (p < 7) {                  // distance-1 register prefetch of next 128-k pair
#pragma unroll
            for (int j = 0; j < 4; ++j) {
                aNxt[j][0] = *(const float4*)(xA + (p + 1) * 128 + j * 32);
                aNxt[j][1] = *(const float4*)(xA + (p + 1) * 128 + j * 32 + 4);
            }
        }
#pragma unroll
        for (int j = 0; j < 4; ++j) {
            const size_t off = (size_t)(p * 4 + j) * 512;
            bf16x8 b0h = *(const bf16x8*)(wB0h + off);   // L2-resident ws
            bf16x8 b0l = *(const bf16x8*)(wB0l + off);
            bf16x8 b1h = *(const bf16x8*)(wB1h + off);
            bf16x8 b1l = *(const bf16x8*)(wB1l + off);
            uint4 uh, ul;
            split8(aCur[j][0], aCur[j][1], uh, ul);
            bf16x8 ah = __builtin_bit_cast(bf16x8, uh);
            bf16x8 al = __builtin_bit_cast(bf16x8, ul);
            acc0 = __builtin_amdgcn_mfma_f32_16x16x32_bf16(ah, b0h, acc0, 0, 0, 0);
            acc0 = __builtin_amdgcn_mfma_f32_16x16x32_bf16(ah, b0l, acc0, 0, 0, 0);
            acc0 = __builtin_amdgcn_mfma_f32_16x16x32_bf16(al, b0h, acc0, 0, 0, 0);
            acc1 = __builtin_amdgcn_mfma_f32_16x16x32_bf16(ah, b1h, acc1, 0, 0, 0);
            acc1 = __builtin_amdgcn_mfma_f32_16x16x32_bf16(ah, b1l, acc1, 0, 0, 0);
            acc1 = __builtin_amdgcn_mfma_f32_16x16x32_bf16(al, b1h, acc1, 0, 0, 0);
        }
        if (p < 7) {
#pragma unroll
            for (int j = 0; j < 4; ++j) {
                aCur[j][0] = aNxt[j][0];
                aCur[j][1] = aNxt[j][1];
            }
        }
    }

    // issue feature-w fp32 fragment loads; phases below cover their latency
    float4 wfa[4], wfb[4];
#pragma unroll
    for (int i = 0; i < 4; ++i) {
        const int nf = (wv * 4 + i) * 16 + ln15;    // feature 0..255
        wfa[i] = *(const float4*)(w + (size_t)nf * DH + g * 8);
        wfb[i] = *(const float4*)(w + (size_t)nf * DH + g * 8 + 4);
    }

    // -------- Phase 2: +bias -> qk LDS (C/D layout: row(tok)=g*4+r, col=ln15) --------
    const int c0 = (nh * 2 + 0) * 16 + ln15;
    const int c1 = (nh * 2 + 1) * 16 + ln15;
    const float bias0 = (c0 < 32) ? bq[c0] : bk[c0 - 32];
    const float bias1 = (c1 < 32) ? bq[c1] : bk[c1 - 32];
#pragma unroll
    for (int r = 0; r < 4; ++r) {
        qk_f[(th * 16 + g * 4 + r) * QS + c0] = acc0[r] + bias0;
        qk_f[(th * 16 + g * 4 + r) * QS + c1] = acc1[r] + bias1;
    }
    __syncthreads();

    // -------- Phase 3: z = q+k (split), lnA = -0.5(|q|^2+|k|^2); 32 tok x 8 grp --------
    {
        const int tok = tid >> 3, grp = tid & 7;
        float4 qv = *(const float4*)&qk_f[tok * QS + grp * 4];
        float4 kv = *(const float4*)&qk_f[tok * QS + 32 + grp * 4];
        float z0 = qv.x + kv.x, z1 = qv.y + kv.y, z2 = qv.z + kv.z, z3 = qv.w + kv.w;
        float pw = qv.x*qv.x + qv.y*qv.y + qv.z*qv.z + qv.w*qv.w
                 + kv.x*kv.x + kv.y*kv.y + kv.z*kv.z + kv.w*kv.w;
        uint2 ph, pl;
        split2(z0, z1, ph.x, pl.x);
        split2(z2, z3, ph.y, pl.y);
        *(uint2*)&zh_s[tok * ZS + grp * 4] = ph;
        *(uint2*)&zl_s[tok * ZS + grp * 4] = pl;
        pw += __shfl_xor(pw, 1);
        pw += __shfl_xor(pw, 2);
        pw += __shfl_xor(pw, 4);
        if (grp == 0) lnA_f[tok] = -0.5f * pw;
    }
    __syncthreads();

    // -------- Phase 4: S[32 tok][256] = z @ w^T (3-pass split); wave wv: features wv*64.. --------
    f32x4 facc[4][2];
#pragma unroll
    for (int i = 0; i < 4; ++i)
#pragma unroll
        for (int mt = 0; mt < 2; ++mt) facc[i][mt] = (f32x4){0.f,0.f,0.f,0.f};

    bf16x8 a_h[2], a_l[2];
#pragma unroll
    for (int mt = 0; mt < 2; ++mt) {
        a_h[mt] = *(const bf16x8*)&zh_s[(mt * 16 + ln15) * ZS + g * 8];
        a_l[mt] = *(const bf16x8*)&zl_s[(mt * 16 + ln15) * ZS + g * 8];
    }
#pragma unroll
    for (int i = 0; i < 4; ++i) {
        uint4 uh, ul;
        split8(wfa[i], wfb[i], uh, ul);
        bf16x8 wh = __builtin_bit_cast(bf16x8, uh);
        bf16x8 wl = __builtin_bit_cast(bf16x8, ul);
#pragma unroll
        for (int mt = 0; mt < 2; ++mt) {
            facc[i][mt] = __builtin_amdgcn_mfma_f32_16x16x32_bf16(a_h[mt], wh, facc[i][mt], 0, 0, 0);
            facc[i][mt] = __builtin_amdgcn_mfma_f32_16x16x32_bf16(a_h[mt], wl, facc[i][mt], 0, 0, 0);
            facc[i][mt] = __builtin_amdgcn_mfma_f32_16x16x32_bf16(a_l[mt], wh, facc[i][mt], 0, 0, 0);
        }
    }

    // -------- Phase 5: R = 0.5*(exp(lnA+s)+exp(lnA-s)) --------
    float lnAv[2][4];
#pragma unroll
    for (int mt = 0; mt < 2; ++mt)
#pragma unroll
        for (int r = 0; r < 4; ++r) lnAv[mt][r] = lnA_f[mt * 16 + g * 4 + r];

#pragma unroll
    for (int i = 0; i < 4; ++i) {
        const int n = (wv * 4 + i) * 16 + ln15;
#pragma unroll
        for (int mt = 0; mt < 2; ++mt) {
#pragma unroll
            for (int r = 0; r < 4; ++r) {
                float s = facc[i][mt][r];
                float R = 0.5f * (__expf(lnAv[mt][r] + s) + __expf(lnAv[mt][r] - s));
                __builtin_nontemporal_store(R, &out[(t0 + mt * 16 + g * 4 + r) * M_FEAT + n]);
            }
        }
    }
}

extern "C" void kernel_launch(void* const* d_in, const int* in_sizes, int n_in,
                              void* d_out, int out_size, void* d_ws, size_t ws_size,
                              hipStream_t stream) {
    const float* x  = (const float*)d_in[0];
    const float* Wq = (const float*)d_in[1];
    const float* bq = (const float*)d_in[2];
    const float* Wk = (const float*)d_in[3];
    const float* bk = (const float*)d_in[4];
    // d_in[5], d_in[6] = Wv, bv: dead in the reference
    const float* w  = (const float*)d_in[7];
    float* out = (float*)d_out;
    short* ws  = (short*)d_ws;   // 256 KB used

    k_prep<<<dim3(32), dim3(256), 0, stream>>>(Wq, Wk, ws);
    k_main<<<dim3(BT / TB), dim3(256), 0, stream>>>(x, bq, bk, ws, w, out);
}

// Round 2
// 125.520 us; speedup vs baseline: 1.1118x; 1.1118x over previous
//
#include <hip/hip_runtime.h>
#include <cstdint>

#define E_DIM   1024
#define DH      32
#define M_FEAT  256
#define BT      16384

typedef __attribute__((ext_vector_type(8))) short bf16x8;
typedef __attribute__((ext_vector_type(4))) float f32x4;

// ws layout (shorts): proj W in MFMA-fragment order, flat = (nt*32 + sub)*512 + lane*8
#define WP_H_OFF 0
#define WP_L_OFF 65536

// ---- cheap 2-term bf16 split: h = trunc16(f), l = trunc16(f - h) ----
__device__ __forceinline__ unsigned perm_hi2(unsigned lo_src, unsigned hi_src) {
#if __has_builtin(__builtin_amdgcn_perm)
    return __builtin_amdgcn_perm(hi_src, lo_src, 0x07060302u);
#else
    return (lo_src >> 16) | (hi_src & 0xFFFF0000u);
#endif
}

__device__ __forceinline__ void split2(float f0, float f1, unsigned& ph, unsigned& pl) {
    unsigned u0 = __builtin_bit_cast(unsigned, f0);
    unsigned u1 = __builtin_bit_cast(unsigned, f1);
    ph = perm_hi2(u0, u1);
    float d0 = f0 - __builtin_bit_cast(float, u0 & 0xFFFF0000u);
    float d1 = f1 - __builtin_bit_cast(float, u1 & 0xFFFF0000u);
    pl = perm_hi2(__builtin_bit_cast(unsigned, d0), __builtin_bit_cast(unsigned, d1));
}

__device__ __forceinline__ void split8(const float4& a, const float4& b,
                                       uint4& uh, uint4& ul) {
    split2(a.x, a.y, uh.x, ul.x);
    split2(a.z, a.w, uh.y, ul.y);
    split2(b.x, b.y, uh.z, ul.z);
    split2(b.z, b.w, uh.w, ul.w);
}

// ---------- prep: 32 blocks, each a 64-k half-slab; LDS transpose -> fragment order ----------
__global__ __launch_bounds__(256) void k_prep(
    const float* __restrict__ Wq, const float* __restrict__ Wk,
    short* __restrict__ ws)
{
    __shared__ float wlds[64 * 36];    // [k 0..63][n 0..31], stride 36 floats
    const int b = blockIdx.x, tid = threadIdx.x;
    const float* __restrict__ src = (b < 16) ? Wq : Wk;
    const int k0 = (b & 15) * 64;
    const int nbase = (b < 16) ? 0 : 32;
#pragma unroll
    for (int it = 0; it < 2; ++it) {               // coalesced read 64x32 floats
        int f = it * 256 + tid;                    // float4 index
        int k = f >> 3, c4 = f & 7;
        float4 v = *(const float4*)(src + (size_t)(k0 + k) * DH + c4 * 4);
        *(float4*)&wlds[k * 36 + c4 * 4] = v;
    }
    __syncthreads();
    const int n = tid >> 3, kq = tid & 7;
    const int n_g = nbase + n;
    const int nt = n_g >> 4, ln = n_g & 15;
#pragma unroll
    for (int rep = 0; rep < 2; ++rep) {
        int kk = rep * 8 + kq;                     // k-quad within this 64-slab
        int k_g = k0 + kk * 4;
        float f0 = wlds[(kk * 4 + 0) * 36 + n];
        float f1 = wlds[(kk * 4 + 1) * 36 + n];
        float f2 = wlds[(kk * 4 + 2) * 36 + n];
        float f3 = wlds[(kk * 4 + 3) * 36 + n];
        uint2 ph, pl;
        split2(f0, f1, ph.x, pl.x);
        split2(f2, f3, ph.y, pl.y);
        int sub = k_g >> 5;                        // global 32-k subchunk 0..31
        int gq = (k_g >> 3) & 3, j0 = k_g & 7;
        int lane = gq * 16 + ln;
        size_t flat = ((size_t)(nt * 32 + sub)) * 512 + lane * 8 + j0;
        *(uint2*)(ws + WP_H_OFF + flat) = ph;
        *(uint2*)(ws + WP_L_OFF + flat) = pl;
    }
}

// ---------- fused main: TB=16 -> grid 1024 (4 blocks/CU), LDS dbuf, inline B ----------
#define TB 16
#define XS2 136  // x LDS row stride in shorts (128 data + 8 pad) = 272 B
#define QS 68    // qk row stride in floats
#define ZS 40    // z row stride in shorts

__global__ __launch_bounds__(256, 4) void k_main(
    const float* __restrict__ x, const float* __restrict__ bq,
    const float* __restrict__ bk, const short* __restrict__ ws,
    const float* __restrict__ w, float* __restrict__ out)
{
    __shared__ __align__(16) short xh_s[2][TB * XS2];
    __shared__ __align__(16) short xl_s[2][TB * XS2];
    __shared__ __align__(16) float qk_f[TB * QS];
    __shared__ __align__(16) short zh_s[TB * ZS];
    __shared__ __align__(16) short zl_s[TB * ZS];
    __shared__ float lnA_f[TB];

    const int tid  = threadIdx.x;
    const int lane = tid & 63;
    const int wv   = __builtin_amdgcn_readfirstlane(tid >> 6);  // 0..3
    const int ln15 = lane & 15;
    const int g    = lane >> 4;                                  // 0..3
    const long t0  = (long)blockIdx.x * TB;

    const int nrow = wv * 16 + ln15;   // proj output column 0..63 (wave wv owns n-tile wv)
    const float bias = (nrow < 32) ? bq[nrow] : bk[nrow - 32];

    // -------- Phase 1: C[16 tok][64] = x @ [Wq|Wk] (3-pass split bf16 MFMA) --------
    const int kq = tid & 15;          // 8-k group 0..15 within 128-wide pair
    const int mr = tid >> 4;          // token row 0..15

    f32x4 acc0 = {0.f, 0.f, 0.f, 0.f};

    const short* wpB_h = ws + WP_H_OFF + (size_t)(wv * 32) * 512 + lane * 8;
    const short* wpB_l = ws + WP_L_OFF + (size_t)(wv * 32) * 512 + lane * 8;
    const float* xr0 = x + (t0 + mr) * (size_t)E_DIM + kq * 8;

    // distance-1 register prefetch into LDS double buffer
    float4 a0 = *(const float4*)(xr0 + 0), b0 = *(const float4*)(xr0 + 4);
    {
        uint4 uh, ul;
        split8(a0, b0, uh, ul);
        *(uint4*)&xh_s[0][mr * XS2 + kq * 8] = uh;
        *(uint4*)&xl_s[0][mr * XS2 + kq * 8] = ul;
    }

#pragma unroll
    for (int p = 0; p < 8; ++p) {
        __syncthreads();              // buf (p&1) fully staged; prior reads of it done
        if (p < 7) {                  // prefetch pair p+1
            a0 = *(const float4*)(xr0 + (p + 1) * 128);
            b0 = *(const float4*)(xr0 + (p + 1) * 128 + 4);
        }
        // B fragments for this pair, inline (L2-resident ws)
#pragma unroll
        for (int j = 0; j < 4; ++j) {
            bf16x8 bh = *(const bf16x8*)(wpB_h + (size_t)(p * 4 + j) * 512);
            bf16x8 bl = *(const bf16x8*)(wpB_l + (size_t)(p * 4 + j) * 512);
            bf16x8 ah0 = *(const bf16x8*)&xh_s[p & 1][ln15 * XS2 + j * 32 + g * 8];
            bf16x8 al0 = *(const bf16x8*)&xl_s[p & 1][ln15 * XS2 + j * 32 + g * 8];
            acc0 = __builtin_amdgcn_mfma_f32_16x16x32_bf16(ah0, bh, acc0, 0, 0, 0);
            acc0 = __builtin_amdgcn_mfma_f32_16x16x32_bf16(ah0, bl, acc0, 0, 0, 0);
            acc0 = __builtin_amdgcn_mfma_f32_16x16x32_bf16(al0, bh, acc0, 0, 0, 0);
        }
        if (p < 7) {                  // stage pair p+1 into the other buffer
            uint4 uh, ul;
            split8(a0, b0, uh, ul);
            *(uint4*)&xh_s[(p + 1) & 1][mr * XS2 + kq * 8] = uh;
            *(uint4*)&xl_s[(p + 1) & 1][mr * XS2 + kq * 8] = ul;
        }
    }

    // issue feature-w fp32 fragment loads; barrier phases below cover their latency
    float4 wfa[4], wfb[4];
#pragma unroll
    for (int i = 0; i < 4; ++i) {
        const int nf = (wv * 4 + i) * 16 + ln15;    // feature 0..255
        wfa[i] = *(const float4*)(w + (size_t)nf * DH + g * 8);
        wfb[i] = *(const float4*)(w + (size_t)nf * DH + g * 8 + 4);
    }

    // -------- Phase 2: +bias -> qk LDS (C/D layout: row(tok)=g*4+r, col=ln15) --------
#pragma unroll
    for (int r = 0; r < 4; ++r) {
        qk_f[(g * 4 + r) * QS + nrow] = acc0[r] + bias;
    }
    __syncthreads();

    // -------- Phase 3: z = q+k (split), lnA = -0.5(|q|^2+|k|^2); 16 tok x 8 grp --------
    if (tid < 128) {
        const int tok = tid >> 3, grp = tid & 7;
        float4 qv = *(const float4*)&qk_f[tok * QS + grp * 4];
        float4 kv = *(const float4*)&qk_f[tok * QS + 32 + grp * 4];
        float z0 = qv.x + kv.x, z1 = qv.y + kv.y, z2 = qv.z + kv.z, z3 = qv.w + kv.w;
        float pw = qv.x*qv.x + qv.y*qv.y + qv.z*qv.z + qv.w*qv.w
                 + kv.x*kv.x + kv.y*kv.y + kv.z*kv.z + kv.w*kv.w;
        uint2 ph, pl;
        split2(z0, z1, ph.x, pl.x);
        split2(z2, z3, ph.y, pl.y);
        *(uint2*)&zh_s[tok * ZS + grp * 4] = ph;
        *(uint2*)&zl_s[tok * ZS + grp * 4] = pl;
        pw += __shfl_xor(pw, 1);
        pw += __shfl_xor(pw, 2);
        pw += __shfl_xor(pw, 4);
        if (grp == 0) lnA_f[tok] = -0.5f * pw;
    }
    __syncthreads();

    // -------- Phase 4: S[16 tok][256] = z @ w^T (3-pass split); wave wv: features wv*64.. --------
    f32x4 facc[4];
#pragma unroll
    for (int i = 0; i < 4; ++i) facc[i] = (f32x4){0.f,0.f,0.f,0.f};

    bf16x8 a_h = *(const bf16x8*)&zh_s[ln15 * ZS + g * 8];
    bf16x8 a_l = *(const bf16x8*)&zl_s[ln15 * ZS + g * 8];
#pragma unroll
    for (int i = 0; i < 4; ++i) {
        uint4 uh, ul;
        split8(wfa[i], wfb[i], uh, ul);
        bf16x8 wh = __builtin_bit_cast(bf16x8, uh);
        bf16x8 wl = __builtin_bit_cast(bf16x8, ul);
        facc[i] = __builtin_amdgcn_mfma_f32_16x16x32_bf16(a_h, wh, facc[i], 0, 0, 0);
        facc[i] = __builtin_amdgcn_mfma_f32_16x16x32_bf16(a_h, wl, facc[i], 0, 0, 0);
        facc[i] = __builtin_amdgcn_mfma_f32_16x16x32_bf16(a_l, wh, facc[i], 0, 0, 0);
    }

    // -------- Phase 5: R = 0.5*(exp(lnA+s)+exp(lnA-s)) --------
    float lnAv[4];
#pragma unroll
    for (int r = 0; r < 4; ++r) lnAv[r] = lnA_f[g * 4 + r];

#pragma unroll
    for (int i = 0; i < 4; ++i) {
        const int n = (wv * 4 + i) * 16 + ln15;
#pragma unroll
        for (int r = 0; r < 4; ++r) {
            float s = facc[i][r];
            float R = 0.5f * (__expf(lnAv[r] + s) + __expf(lnAv[r] - s));
            __builtin_nontemporal_store(R, &out[(t0 + g * 4 + r) * M_FEAT + n]);
        }
    }
}

extern "C" void kernel_launch(void* const* d_in, const int* in_sizes, int n_in,
                              void* d_out, int out_size, void* d_ws, size_t ws_size,
                              hipStream_t stream) {
    const float* x  = (const float*)d_in[0];
    const float* Wq = (const float*)d_in[1];
    const float* bq = (const float*)d_in[2];
    const float* Wk = (const float*)d_in[3];
    const float* bk = (const float*)d_in[4];
    // d_in[5], d_in[6] = Wv, bv: dead in the reference
    const float* w  = (const float*)d_in[7];
    float* out = (float*)d_out;
    short* ws  = (short*)d_ws;   // 256 KB used

    k_prep<<<dim3(32), dim3(256), 0, stream>>>(Wq, Wk, ws);
    k_main<<<dim3(BT / TB), dim3(256), 0, stream>>>(x, bq, bk, ws, w, out);
}

// Round 3
// 120.857 us; speedup vs baseline: 1.1546x; 1.0386x over previous
//
#include <hip/hip_runtime.h>
#include <cstdint>

#define E_DIM   1024
#define DH      32
#define M_FEAT  256
#define BT      16384

typedef __attribute__((ext_vector_type(8))) _Float16 f16x8;
typedef __attribute__((ext_vector_type(4))) float f32x4;

// ws layout (shorts=fp16): proj W in MFMA-fragment order, flat = (nt*32 + sub)*512 + lane*8
// single fp16 panel (no l-term for weights), 128 KB total

__device__ __forceinline__ unsigned packh2(_Float16 a, _Float16 b) {
    union { _Float16 h[2]; unsigned u; } t;
    t.h[0] = a; t.h[1] = b;
    return t.u;
}

// x/z 2-term fp16 split: h = fp16_rne(f), l = fp16_rne(f - h)
__device__ __forceinline__ void splitf16_2(float f0, float f1, unsigned& ph, unsigned& pl) {
    _Float16 h0 = (_Float16)f0, h1 = (_Float16)f1;
    float l0 = f0 - (float)h0, l1 = f1 - (float)h1;
    ph = packh2(h0, h1);
    pl = packh2((_Float16)l0, (_Float16)l1);
}

__device__ __forceinline__ void splitf16_8(const float4& a, const float4& b,
                                           uint4& uh, uint4& ul) {
    splitf16_2(a.x, a.y, uh.x, ul.x);
    splitf16_2(a.z, a.w, uh.y, ul.y);
    splitf16_2(b.x, b.y, uh.z, ul.z);
    splitf16_2(b.z, b.w, uh.w, ul.w);
}

// ---------- prep: 32 blocks, each a 64-k half-slab; LDS transpose -> fp16 fragment order ----------
__global__ __launch_bounds__(256) void k_prep(
    const float* __restrict__ Wq, const float* __restrict__ Wk,
    short* __restrict__ ws)
{
    __shared__ float wlds[64 * 36];    // [k 0..63][n 0..31], stride 36 floats
    const int b = blockIdx.x, tid = threadIdx.x;
    const float* __restrict__ src = (b < 16) ? Wq : Wk;
    const int k0 = (b & 15) * 64;
    const int nbase = (b < 16) ? 0 : 32;
#pragma unroll
    for (int it = 0; it < 2; ++it) {               // coalesced read 64x32 floats
        int f = it * 256 + tid;                    // float4 index
        int k = f >> 3, c4 = f & 7;
        float4 v = *(const float4*)(src + (size_t)(k0 + k) * DH + c4 * 4);
        *(float4*)&wlds[k * 36 + c4 * 4] = v;
    }
    __syncthreads();
    const int n = tid >> 3, kq = tid & 7;
    const int n_g = nbase + n;
    const int nt = n_g >> 4, ln = n_g & 15;
#pragma unroll
    for (int rep = 0; rep < 2; ++rep) {
        int kk = rep * 8 + kq;                     // k-quad within this 64-slab
        int k_g = k0 + kk * 4;
        float f0 = wlds[(kk * 4 + 0) * 36 + n];
        float f1 = wlds[(kk * 4 + 1) * 36 + n];
        float f2 = wlds[(kk * 4 + 2) * 36 + n];
        float f3 = wlds[(kk * 4 + 3) * 36 + n];
        uint2 ph;
        ph.x = packh2((_Float16)f0, (_Float16)f1); // RNE fp16, err <= 2^-12 rel
        ph.y = packh2((_Float16)f2, (_Float16)f3);
        int sub = k_g >> 5;                        // global 32-k subchunk 0..31
        int gq = (k_g >> 3) & 3, j0 = k_g & 7;
        int lane = gq * 16 + ln;
        size_t flat = ((size_t)(nt * 32 + sub)) * 512 + lane * 8 + j0;
        *(uint2*)(ws + flat) = ph;
    }
}

// ---------- fused main: TB=32 (r0 champion structure), fp16 2-pass MFMA ----------
#define TB 32
#define XS2 136  // x LDS row stride in shorts (128 data + 8 pad) = 272 B
#define QS 68    // qk row stride in floats
#define ZS 40    // z row stride in shorts

__global__ __launch_bounds__(256, 3) void k_main(
    const float* __restrict__ x, const float* __restrict__ bq,
    const float* __restrict__ bk, const short* __restrict__ ws,
    const float* __restrict__ w, float* __restrict__ out)
{
    __shared__ __align__(16) short xh_s[2][TB * XS2];
    __shared__ __align__(16) short xl_s[2][TB * XS2];
    __shared__ __align__(16) float qk_f[TB * QS];
    __shared__ __align__(16) short zh_s[TB * ZS];
    __shared__ __align__(16) short zl_s[TB * ZS];
    __shared__ float lnA_f[TB];

    const int tid  = threadIdx.x;
    const int lane = tid & 63;
    const int wv   = __builtin_amdgcn_readfirstlane(tid >> 6);  // 0..3
    const int ln15 = lane & 15;
    const int g    = lane >> 4;                                  // 0..3
    const long t0  = (long)blockIdx.x * TB;

    const int nrow = wv * 16 + ln15;   // proj output column 0..63
    const float bias = (nrow < 32) ? bq[nrow] : bk[nrow - 32];

    // -------- Phase 1: C[32 tok][64] = x @ [Wq|Wk] (fp16 2-pass: xh*W + xl*W) --------
    const int kq = tid & 15;          // 8-k group 0..15 within 128-wide pair
    const int mr = tid >> 4;          // token row 0..15 (also handles mr+16)

    f32x4 acc0 = {0.f, 0.f, 0.f, 0.f};   // tokens 0..15
    f32x4 acc1 = {0.f, 0.f, 0.f, 0.f};   // tokens 16..31

    const short* wpB = ws + (size_t)(wv * 32) * 512 + lane * 8;
    const float* xr0 = x + (t0 + mr) * (size_t)E_DIM + kq * 8;
    const float* xr1 = x + (t0 + mr + 16) * (size_t)E_DIM + kq * 8;

    // distance-1 x register prefetch
    float4 a0 = *(const float4*)(xr0 + 0), b0 = *(const float4*)(xr0 + 4);
    float4 a1 = *(const float4*)(xr1 + 0), b1 = *(const float4*)(xr1 + 4);
    {
        uint4 uh, ul;
        splitf16_8(a0, b0, uh, ul);
        *(uint4*)&xh_s[0][mr * XS2 + kq * 8] = uh;
        *(uint4*)&xl_s[0][mr * XS2 + kq * 8] = ul;
        splitf16_8(a1, b1, uh, ul);
        *(uint4*)&xh_s[0][(mr + 16) * XS2 + kq * 8] = uh;
        *(uint4*)&xl_s[0][(mr + 16) * XS2 + kq * 8] = ul;
    }

#pragma unroll
    for (int p = 0; p < 8; ++p) {
        __syncthreads();              // buf (p&1) fully staged; prior reads of it done
        if (p < 7) {                  // prefetch pair p+1
            a0 = *(const float4*)(xr0 + (p + 1) * 128);
            b0 = *(const float4*)(xr0 + (p + 1) * 128 + 4);
            a1 = *(const float4*)(xr1 + (p + 1) * 128);
            b1 = *(const float4*)(xr1 + (p + 1) * 128 + 4);
        }
        // B fragments for this pair, inline (L2-resident ws, single fp16 panel)
#pragma unroll
        for (int j = 0; j < 4; ++j) {
            f16x8 bh = *(const f16x8*)(wpB + (size_t)(p * 4 + j) * 512);
            f16x8 ah0 = *(const f16x8*)&xh_s[p & 1][ln15 * XS2 + j * 32 + g * 8];
            f16x8 al0 = *(const f16x8*)&xl_s[p & 1][ln15 * XS2 + j * 32 + g * 8];
            f16x8 ah1 = *(const f16x8*)&xh_s[p & 1][(ln15 + 16) * XS2 + j * 32 + g * 8];
            f16x8 al1 = *(const f16x8*)&xl_s[p & 1][(ln15 + 16) * XS2 + j * 32 + g * 8];
            acc0 = __builtin_amdgcn_mfma_f32_16x16x32_f16(ah0, bh, acc0, 0, 0, 0);
            acc0 = __builtin_amdgcn_mfma_f32_16x16x32_f16(al0, bh, acc0, 0, 0, 0);
            acc1 = __builtin_amdgcn_mfma_f32_16x16x32_f16(ah1, bh, acc1, 0, 0, 0);
            acc1 = __builtin_amdgcn_mfma_f32_16x16x32_f16(al1, bh, acc1, 0, 0, 0);
        }
        if (p < 7) {                  // stage pair p+1 into the other buffer
            uint4 uh, ul;
            splitf16_8(a0, b0, uh, ul);
            *(uint4*)&xh_s[(p + 1) & 1][mr * XS2 + kq * 8] = uh;
            *(uint4*)&xl_s[(p + 1) & 1][mr * XS2 + kq * 8] = ul;
            splitf16_8(a1, b1, uh, ul);
            *(uint4*)&xh_s[(p + 1) & 1][(mr + 16) * XS2 + kq * 8] = uh;
            *(uint4*)&xl_s[(p + 1) & 1][(mr + 16) * XS2 + kq * 8] = ul;
        }
    }

    // issue feature-w fp32 fragment loads; barrier phases below cover their latency
    float4 wfa[4], wfb[4];
#pragma unroll
    for (int i = 0; i < 4; ++i) {
        const int nf = (wv * 4 + i) * 16 + ln15;    // feature 0..255
        wfa[i] = *(const float4*)(w + (size_t)nf * DH + g * 8);
        wfb[i] = *(const float4*)(w + (size_t)nf * DH + g * 8 + 4);
    }

    // -------- Phase 2: +bias -> qk LDS (C/D layout: row(tok)=g*4+r, col=ln15) --------
#pragma unroll
    for (int r = 0; r < 4; ++r) {
        qk_f[(g * 4 + r) * QS + nrow]        = acc0[r] + bias;
        qk_f[(16 + g * 4 + r) * QS + nrow]   = acc1[r] + bias;
    }
    __syncthreads();

    // -------- Phase 3: z = q+k (fp16 split), lnA = -0.5(|q|^2+|k|^2); 32 tok x 8 grp --------
    {
        const int tok = tid >> 3, grp = tid & 7;
        float4 qv = *(const float4*)&qk_f[tok * QS + grp * 4];
        float4 kv = *(const float4*)&qk_f[tok * QS + 32 + grp * 4];
        float z0 = qv.x + kv.x, z1 = qv.y + kv.y, z2 = qv.z + kv.z, z3 = qv.w + kv.w;
        float pw = qv.x*qv.x + qv.y*qv.y + qv.z*qv.z + qv.w*qv.w
                 + kv.x*kv.x + kv.y*kv.y + kv.z*kv.z + kv.w*kv.w;
        uint2 ph, pl;
        splitf16_2(z0, z1, ph.x, pl.x);
        splitf16_2(z2, z3, ph.y, pl.y);
        *(uint2*)&zh_s[tok * ZS + grp * 4] = ph;
        *(uint2*)&zl_s[tok * ZS + grp * 4] = pl;
        pw += __shfl_xor(pw, 1);
        pw += __shfl_xor(pw, 2);
        pw += __shfl_xor(pw, 4);
        if (grp == 0) lnA_f[tok] = -0.5f * pw;
    }
    __syncthreads();

    // -------- Phase 4: S[32 tok][256] = z @ w^T (fp16 2-pass); wave wv: features wv*64.. --------
    f32x4 facc[4][2];
#pragma unroll
    for (int i = 0; i < 4; ++i)
#pragma unroll
        for (int mt = 0; mt < 2; ++mt) facc[i][mt] = (f32x4){0.f,0.f,0.f,0.f};

    f16x8 a_h[2], a_l[2];
#pragma unroll
    for (int mt = 0; mt < 2; ++mt) {
        a_h[mt] = *(const f16x8*)&zh_s[(mt * 16 + ln15) * ZS + g * 8];
        a_l[mt] = *(const f16x8*)&zl_s[(mt * 16 + ln15) * ZS + g * 8];
    }
#pragma unroll
    for (int i = 0; i < 4; ++i) {
        uint4 uw;
        uw.x = packh2((_Float16)wfa[i].x, (_Float16)wfa[i].y);
        uw.y = packh2((_Float16)wfa[i].z, (_Float16)wfa[i].w);
        uw.z = packh2((_Float16)wfb[i].x, (_Float16)wfb[i].y);
        uw.w = packh2((_Float16)wfb[i].z, (_Float16)wfb[i].w);
        f16x8 w8 = __builtin_bit_cast(f16x8, uw);
#pragma unroll
        for (int mt = 0; mt < 2; ++mt) {
            facc[i][mt] = __builtin_amdgcn_mfma_f32_16x16x32_f16(a_h[mt], w8, facc[i][mt], 0, 0, 0);
            facc[i][mt] = __builtin_amdgcn_mfma_f32_16x16x32_f16(a_l[mt], w8, facc[i][mt], 0, 0, 0);
        }
    }

    // -------- Phase 5: R = 0.5*(exp(lnA+s)+exp(lnA-s)) --------
    float lnAv[2][4];
#pragma unroll
    for (int mt = 0; mt < 2; ++mt)
#pragma unroll
        for (int r = 0; r < 4; ++r) lnAv[mt][r] = lnA_f[mt * 16 + g * 4 + r];

#pragma unroll
    for (int i = 0; i < 4; ++i) {
        const int n = (wv * 4 + i) * 16 + ln15;
#pragma unroll
        for (int mt = 0; mt < 2; ++mt) {
#pragma unroll
            for (int r = 0; r < 4; ++r) {
                float s = facc[i][mt][r];
                float R = 0.5f * (__expf(lnAv[mt][r] + s) + __expf(lnAv[mt][r] - s));
                __builtin_nontemporal_store(R, &out[(t0 + mt * 16 + g * 4 + r) * M_FEAT + n]);
            }
        }
    }
}

extern "C" void kernel_launch(void* const* d_in, const int* in_sizes, int n_in,
                              void* d_out, int out_size, void* d_ws, size_t ws_size,
                              hipStream_t stream) {
    const float* x  = (const float*)d_in[0];
    const float* Wq = (const float*)d_in[1];
    const float* bq = (const float*)d_in[2];
    const float* Wk = (const float*)d_in[3];
    const float* bk = (const float*)d_in[4];
    // d_in[5], d_in[6] = Wv, bv: dead in the reference
    const float* w  = (const float*)d_in[7];
    float* out = (float*)d_out;
    short* ws  = (short*)d_ws;   // 128 KB used (single fp16 weight panel)

    k_prep<<<dim3(32), dim3(256), 0, stream>>>(Wq, Wk, ws);
    k_main<<<dim3(BT / TB), dim3(256), 0, stream>>>(x, bq, bk, ws, w, out);
}

// Round 4
// 118.147 us; speedup vs baseline: 1.1811x; 1.0229x over previous
//
#include <hip/hip_runtime.h>
#include <cstdint>

#define E_DIM   1024
#define DH      32
#define M_FEAT  256
#define BT      16384

typedef __attribute__((ext_vector_type(8))) _Float16 f16x8;
typedef __attribute__((ext_vector_type(4))) float f32x4;

// ws layout (shorts=fp16): proj W in MFMA-fragment order, flat = (nt*32 + sub)*512 + lane*8
// single fp16 panel (no l-term for weights), 128 KB total

__device__ __forceinline__ unsigned packh2(_Float16 a, _Float16 b) {
    union { _Float16 h[2]; unsigned u; } t;
    t.h[0] = a; t.h[1] = b;
    return t.u;
}

// x/z 2-term fp16 split: h = fp16_rne(f), l = fp16_rne(f - h)
__device__ __forceinline__ void splitf16_2(float f0, float f1, unsigned& ph, unsigned& pl) {
    _Float16 h0 = (_Float16)f0, h1 = (_Float16)f1;
    float l0 = f0 - (float)h0, l1 = f1 - (float)h1;
    ph = packh2(h0, h1);
    pl = packh2((_Float16)l0, (_Float16)l1);
}

__device__ __forceinline__ void splitf16_8(const float4& a, const float4& b,
                                           uint4& uh, uint4& ul) {
    splitf16_2(a.x, a.y, uh.x, ul.x);
    splitf16_2(a.z, a.w, uh.y, ul.y);
    splitf16_2(b.x, b.y, uh.z, ul.z);
    splitf16_2(b.z, b.w, uh.w, ul.w);
}

// ---------- prep: 32 blocks, each a 64-k half-slab; LDS transpose -> fp16 fragment order ----------
__global__ __launch_bounds__(256) void k_prep(
    const float* __restrict__ Wq, const float* __restrict__ Wk,
    short* __restrict__ ws)
{
    __shared__ float wlds[64 * 36];    // [k 0..63][n 0..31], stride 36 floats
    const int b = blockIdx.x, tid = threadIdx.x;
    const float* __restrict__ src = (b < 16) ? Wq : Wk;
    const int k0 = (b & 15) * 64;
    const int nbase = (b < 16) ? 0 : 32;
#pragma unroll
    for (int it = 0; it < 2; ++it) {               // coalesced read 64x32 floats
        int f = it * 256 + tid;                    // float4 index
        int k = f >> 3, c4 = f & 7;
        float4 v = *(const float4*)(src + (size_t)(k0 + k) * DH + c4 * 4);
        *(float4*)&wlds[k * 36 + c4 * 4] = v;
    }
    __syncthreads();
    const int n = tid >> 3, kq = tid & 7;
    const int n_g = nbase + n;
    const int nt = n_g >> 4, ln = n_g & 15;
#pragma unroll
    for (int rep = 0; rep < 2; ++rep) {
        int kk = rep * 8 + kq;                     // k-quad within this 64-slab
        int k_g = k0 + kk * 4;
        float f0 = wlds[(kk * 4 + 0) * 36 + n];
        float f1 = wlds[(kk * 4 + 1) * 36 + n];
        float f2 = wlds[(kk * 4 + 2) * 36 + n];
        float f3 = wlds[(kk * 4 + 3) * 36 + n];
        uint2 ph;
        ph.x = packh2((_Float16)f0, (_Float16)f1); // RNE fp16, err <= 2^-12 rel
        ph.y = packh2((_Float16)f2, (_Float16)f3);
        int sub = k_g >> 5;                        // global 32-k subchunk 0..31
        int gq = (k_g >> 3) & 3, j0 = k_g & 7;
        int lane = gq * 16 + ln;
        size_t flat = ((size_t)(nt * 32 + sub)) * 512 + lane * 8 + j0;
        *(uint2*)(ws + flat) = ph;
    }
}

// ---------- fused main: TB=32, fp16 2-pass MFMA, DISTANCE-2 register prefetch ----------
#define TB 32
#define XS2 136  // x LDS row stride in shorts (128 data + 8 pad) = 272 B
#define QS 68    // qk row stride in floats
#define ZS 40    // z row stride in shorts

__global__ __launch_bounds__(256, 3) void k_main(
    const float* __restrict__ x, const float* __restrict__ bq,
    const float* __restrict__ bk, const short* __restrict__ ws,
    const float* __restrict__ w, float* __restrict__ out)
{
    __shared__ __align__(16) short xh_s[2][TB * XS2];
    __shared__ __align__(16) short xl_s[2][TB * XS2];
    __shared__ __align__(16) float qk_f[TB * QS];
    __shared__ __align__(16) short zh_s[TB * ZS];
    __shared__ __align__(16) short zl_s[TB * ZS];
    __shared__ float lnA_f[TB];

    const int tid  = threadIdx.x;
    const int lane = tid & 63;
    const int wv   = __builtin_amdgcn_readfirstlane(tid >> 6);  // 0..3
    const int ln15 = lane & 15;
    const int g    = lane >> 4;                                  // 0..3
    const long t0  = (long)blockIdx.x * TB;

    const int nrow = wv * 16 + ln15;   // proj output column 0..63
    const float bias = (nrow < 32) ? bq[nrow] : bk[nrow - 32];

    // -------- Phase 1: C[32 tok][64] = x @ [Wq|Wk] (fp16 2-pass), distance-2 pipeline --------
    const int kq = tid & 15;          // 8-k group 0..15 within 128-wide pair
    const int mr = tid >> 4;          // token row 0..15 (also handles mr+16)

    f32x4 acc0 = {0.f, 0.f, 0.f, 0.f};   // tokens 0..15
    f32x4 acc1 = {0.f, 0.f, 0.f, 0.f};   // tokens 16..31

    const short* wpB = ws + (size_t)(wv * 32) * 512 + lane * 8;
    const float* xr0 = x + (t0 + mr) * (size_t)E_DIM + kq * 8;
    const float* xr1 = x + (t0 + mr + 16) * (size_t)E_DIM + kq * 8;

    // two live prefetch sets; pair k lives in set parity (k&1)
    float4 s0[4], s1[4];
    {
        // pair 0 -> temps (consumed immediately); pair 1 -> s1 (overlaps pair-0 split)
        float4 t0v = *(const float4*)(xr0 + 0), t1v = *(const float4*)(xr0 + 4);
        float4 t2v = *(const float4*)(xr1 + 0), t3v = *(const float4*)(xr1 + 4);
        s1[0] = *(const float4*)(xr0 + 128);
        s1[1] = *(const float4*)(xr0 + 132);
        s1[2] = *(const float4*)(xr1 + 128);
        s1[3] = *(const float4*)(xr1 + 132);
        uint4 uh, ul;
        splitf16_8(t0v, t1v, uh, ul);
        *(uint4*)&xh_s[0][mr * XS2 + kq * 8] = uh;
        *(uint4*)&xl_s[0][mr * XS2 + kq * 8] = ul;
        splitf16_8(t2v, t3v, uh, ul);
        *(uint4*)&xh_s[0][(mr + 16) * XS2 + kq * 8] = uh;
        *(uint4*)&xl_s[0][(mr + 16) * XS2 + kq * 8] = ul;
    }

#pragma unroll
    for (int p = 0; p < 8; ++p) {
        __syncthreads();              // LDS buf (p&1) fully staged; prior reads of it done
        // issue pair p+2 into set parity (p+2)&1 == p&1 (its old pair was consumed last phase)
        if (p < 6) {
            float4* d = (p & 1) ? s1 : s0;
            d[0] = *(const float4*)(xr0 + (p + 2) * 128);
            d[1] = *(const float4*)(xr0 + (p + 2) * 128 + 4);
            d[2] = *(const float4*)(xr1 + (p + 2) * 128);
            d[3] = *(const float4*)(xr1 + (p + 2) * 128 + 4);
        }
        // preload all B fragments for this pair (L2-resident; latency overlapped across j)
        f16x8 bfr[4];
#pragma unroll
        for (int j = 0; j < 4; ++j)
            bfr[j] = *(const f16x8*)(wpB + (size_t)(p * 4 + j) * 512);
#pragma unroll
        for (int j = 0; j < 4; ++j) {
            f16x8 ah0 = *(const f16x8*)&xh_s[p & 1][ln15 * XS2 + j * 32 + g * 8];
            f16x8 al0 = *(const f16x8*)&xl_s[p & 1][ln15 * XS2 + j * 32 + g * 8];
            f16x8 ah1 = *(const f16x8*)&xh_s[p & 1][(ln15 + 16) * XS2 + j * 32 + g * 8];
            f16x8 al1 = *(const f16x8*)&xl_s[p & 1][(ln15 + 16) * XS2 + j * 32 + g * 8];
            acc0 = __builtin_amdgcn_mfma_f32_16x16x32_f16(ah0, bfr[j], acc0, 0, 0, 0);
            acc0 = __builtin_amdgcn_mfma_f32_16x16x32_f16(al0, bfr[j], acc0, 0, 0, 0);
            acc1 = __builtin_amdgcn_mfma_f32_16x16x32_f16(ah1, bfr[j], acc1, 0, 0, 0);
            acc1 = __builtin_amdgcn_mfma_f32_16x16x32_f16(al1, bfr[j], acc1, 0, 0, 0);
        }
        // stage pair p+1 (issued one full phase ago -> ~zero vmcnt wait) into buf (p+1)&1
        if (p < 7) {
            const float4* s = ((p + 1) & 1) ? s1 : s0;
            uint4 uh, ul;
            splitf16_8(s[0], s[1], uh, ul);
            *(uint4*)&xh_s[(p + 1) & 1][mr * XS2 + kq * 8] = uh;
            *(uint4*)&xl_s[(p + 1) & 1][mr * XS2 + kq * 8] = ul;
            splitf16_8(s[2], s[3], uh, ul);
            *(uint4*)&xh_s[(p + 1) & 1][(mr + 16) * XS2 + kq * 8] = uh;
            *(uint4*)&xl_s[(p + 1) & 1][(mr + 16) * XS2 + kq * 8] = ul;
        }
    }

    // issue feature-w fp32 fragment loads; barrier phases below cover their latency
    float4 wfa[4], wfb[4];
#pragma unroll
    for (int i = 0; i < 4; ++i) {
        const int nf = (wv * 4 + i) * 16 + ln15;    // feature 0..255
        wfa[i] = *(const float4*)(w + (size_t)nf * DH + g * 8);
        wfb[i] = *(const float4*)(w + (size_t)nf * DH + g * 8 + 4);
    }

    // -------- Phase 2: +bias -> qk LDS (C/D layout: row(tok)=g*4+r, col=ln15) --------
#pragma unroll
    for (int r = 0; r < 4; ++r) {
        qk_f[(g * 4 + r) * QS + nrow]        = acc0[r] + bias;
        qk_f[(16 + g * 4 + r) * QS + nrow]   = acc1[r] + bias;
    }
    __syncthreads();

    // -------- Phase 3: z = q+k (fp16 split), lnA = -0.5(|q|^2+|k|^2); 32 tok x 8 grp --------
    {
        const int tok = tid >> 3, grp = tid & 7;
        float4 qv = *(const float4*)&qk_f[tok * QS + grp * 4];
        float4 kv = *(const float4*)&qk_f[tok * QS + 32 + grp * 4];
        float z0 = qv.x + kv.x, z1 = qv.y + kv.y, z2 = qv.z + kv.z, z3 = qv.w + kv.w;
        float pw = qv.x*qv.x + qv.y*qv.y + qv.z*qv.z + qv.w*qv.w
                 + kv.x*kv.x + kv.y*kv.y + kv.z*kv.z + kv.w*kv.w;
        uint2 ph, pl;
        splitf16_2(z0, z1, ph.x, pl.x);
        splitf16_2(z2, z3, ph.y, pl.y);
        *(uint2*)&zh_s[tok * ZS + grp * 4] = ph;
        *(uint2*)&zl_s[tok * ZS + grp * 4] = pl;
        pw += __shfl_xor(pw, 1);
        pw += __shfl_xor(pw, 2);
        pw += __shfl_xor(pw, 4);
        if (grp == 0) lnA_f[tok] = -0.5f * pw;
    }
    __syncthreads();

    // -------- Phase 4: S[32 tok][256] = z @ w^T (fp16 2-pass); wave wv: features wv*64.. --------
    f32x4 facc[4][2];
#pragma unroll
    for (int i = 0; i < 4; ++i)
#pragma unroll
        for (int mt = 0; mt < 2; ++mt) facc[i][mt] = (f32x4){0.f,0.f,0.f,0.f};

    f16x8 a_h[2], a_l[2];
#pragma unroll
    for (int mt = 0; mt < 2; ++mt) {
        a_h[mt] = *(const f16x8*)&zh_s[(mt * 16 + ln15) * ZS + g * 8];
        a_l[mt] = *(const f16x8*)&zl_s[(mt * 16 + ln15) * ZS + g * 8];
    }
#pragma unroll
    for (int i = 0; i < 4; ++i) {
        uint4 uw;
        uw.x = packh2((_Float16)wfa[i].x, (_Float16)wfa[i].y);
        uw.y = packh2((_Float16)wfa[i].z, (_Float16)wfa[i].w);
        uw.z = packh2((_Float16)wfb[i].x, (_Float16)wfb[i].y);
        uw.w = packh2((_Float16)wfb[i].z, (_Float16)wfb[i].w);
        f16x8 w8 = __builtin_bit_cast(f16x8, uw);
#pragma unroll
        for (int mt = 0; mt < 2; ++mt) {
            facc[i][mt] = __builtin_amdgcn_mfma_f32_16x16x32_f16(a_h[mt], w8, facc[i][mt], 0, 0, 0);
            facc[i][mt] = __builtin_amdgcn_mfma_f32_16x16x32_f16(a_l[mt], w8, facc[i][mt], 0, 0, 0);
        }
    }

    // -------- Phase 5: R = 0.5*(exp(lnA+s)+exp(lnA-s)) --------
    float lnAv[2][4];
#pragma unroll
    for (int mt = 0; mt < 2; ++mt)
#pragma unroll
        for (int r = 0; r < 4; ++r) lnAv[mt][r] = lnA_f[mt * 16 + g * 4 + r];

#pragma unroll
    for (int i = 0; i < 4; ++i) {
        const int n = (wv * 4 + i) * 16 + ln15;
#pragma unroll
        for (int mt = 0; mt < 2; ++mt) {
#pragma unroll
            for (int r = 0; r < 4; ++r) {
                float s = facc[i][mt][r];
                float R = 0.5f * (__expf(lnAv[mt][r] + s) + __expf(lnAv[mt][r] - s));
                __builtin_nontemporal_store(R, &out[(t0 + mt * 16 + g * 4 + r) * M_FEAT + n]);
            }
        }
    }
}

extern "C" void kernel_launch(void* const* d_in, const int* in_sizes, int n_in,
                              void* d_out, int out_size, void* d_ws, size_t ws_size,
                              hipStream_t stream) {
    const float* x  = (const float*)d_in[0];
    const float* Wq = (const float*)d_in[1];
    const float* bq = (const float*)d_in[2];
    const float* Wk = (const float*)d_in[3];
    const float* bk = (const float*)d_in[4];
    // d_in[5], d_in[6] = Wv, bv: dead in the reference
    const float* w  = (const float*)d_in[7];
    float* out = (float*)d_out;
    short* ws  = (short*)d_ws;   // 128 KB used (single fp16 weight panel)

    k_prep<<<dim3(32), dim3(256), 0, stream>>>(Wq, Wk, ws);
    k_main<<<dim3(BT / TB), dim3(256), 0, stream>>>(x, bq, bk, ws, w, out);
}